// Round 4
// baseline (241.294 us; speedup 1.0000x reference)
//
#include <hip/hip_runtime.h>
#include <hip/hip_bf16.h>

#define HP    66
#define QTOT  (HP*HP)          // 4356
#define LSTR  67               // padded LDS row stride
#define NWIN  29
#define NW    (NWIN*NWIN)      // 841
#define KK    7
#define WOFF2 14
#define NZ    15               // dy-chunks for contraction
#define NSEG  264              // 66 rows/cols x 4 segments of <=17 (k_dist)
#define QB    8                // queries per k_weights block
#define NIT   27               // ceil(841/32)

// ws float layout:
// 0        : ye66   8*QTOT
// 8*QTOT   : xe66   8*QTOT
// 16*QTOT  : x66p   8*QTOT
// 24*QTOT  : sqye   QTOT
// 25*QTOT  : sqxe   QTOT
// 26*QTOT  : lt66   QTOT
// 27*QTOT  : n2q    QTOT
// 28*QTOT  : n2db   QTOT
// 29*QTOT  : ltb    QTOT
// 30*QTOT  : dist   NW*QTOT f32      (reused as accb2 after k_weights)
// 30*QTOT + NW*QTOT : wf  KK*NW*QTOT bf16

__global__ __launch_bounds__(256) void k_prep1(const float* __restrict__ x,
    const float* __restrict__ xe, const float* __restrict__ ye,
    const float* __restrict__ lt, float* __restrict__ ws) {
  int p = blockIdx.x * 256 + threadIdx.x;
  if (p >= QTOT) return;
  int i = p / HP, j = p % HP;
  bool in = (i >= 1 && i < HP-1 && j >= 1 && j < HP-1);
  int src = (i-1)*64 + (j-1);
  float* ye66 = ws;
  float* xe66 = ws + 8*QTOT;
  float* x66p = ws + 16*QTOT;
  float sy = 0.f, sx = 0.f;
#pragma unroll
  for (int e = 0; e < 8; ++e) {
    float vy = in ? ye[e*4096 + src] : 0.f;
    float vx = in ? xe[e*4096 + src] : 0.f;
    float vv = in ? x [e*4096 + src] : 0.f;
    ye66[e*QTOT + p] = vy;
    xe66[e*QTOT + p] = vx;
    x66p[e*QTOT + p] = vv;
    sy += vy*vy; sx += vx*vx;
  }
  ws[24*QTOT + p] = sy;
  ws[25*QTOT + p] = sx;
  ws[26*QTOT + p] = in ? lt[src] : 0.f;
}

__global__ __launch_bounds__(256) void k_prep2(float* __restrict__ ws) {
  int p = blockIdx.x * 256 + threadIdx.x;
  if (p >= QTOT) return;
  int i = p / HP, j = p % HP;
  const float* sqye = ws + 24*QTOT;
  const float* sqxe = ws + 25*QTOT;
  const float* lt66 = ws + 26*QTOT;
  float a = 0.f, b = 0.f, c = 0.f;
  for (int u = -5; u <= 4; ++u) {
    int ii = i + u; if (ii < 0 || ii >= HP) continue;
    for (int v = -5; v <= 4; ++v) {
      int jj = j + v; if (jj < 0 || jj >= HP) continue;
      int o = ii*HP + jj;
      a += sqye[o]; b += sqxe[o]; c += lt66[o];
    }
  }
  ws[27*QTOT + p] = a;
  ws[28*QTOT + p] = b;
  ws[29*QTOT + p] = c * 0.01f;
}

// one block per shift w: dist plane [w][q]; sliding-window separable box
__global__ __launch_bounds__(256) void k_dist(const float* __restrict__ ws,
                                              float* __restrict__ dist) {
  __shared__ float s[HP*LSTR];
  __shared__ float h[HP*LSTR];
  int w = blockIdx.x, tid = threadIdx.x;
  int dy = w / NWIN - WOFF2, dx = w % NWIN - WOFF2;
  const float* ye66 = ws;
  const float* xe66 = ws + 8*QTOT;
  const float* n2q  = ws + 27*QTOT;
  const float* n2db = ws + 28*QTOT;
  for (int p = tid; p < QTOT; p += 256) {
    int i = p / HP, j = p % HP;
    int ii = i + dy, jj = j + dx;
    float sv = 0.f;
    if (ii >= 0 && ii < HP && jj >= 0 && jj < HP) {
      int p2 = ii*HP + jj;
#pragma unroll
      for (int e = 0; e < 8; ++e) sv += ye66[e*QTOT + p] * xe66[e*QTOT + p2];
    }
    s[i*LSTR + j] = sv;
  }
  __syncthreads();
  for (int t = tid; t < NSEG; t += 256) {
    int row = t % HP, seg = t / HP;
    int c0 = seg * 17, c1 = min(c0 + 17, HP);
    const float* ar = s + row*LSTR;
    float* hr = h + row*LSTR;
    float sum = 0.f;
    for (int j = max(c0-5, 0); j <= min(c0+3, HP-1); ++j) sum += ar[j];
    for (int j = c0; j < c1; ++j) {
      if (j+4 < HP) sum += ar[j+4];
      hr[j] = sum;
      if (j-5 >= 0) sum -= ar[j-5];
    }
  }
  __syncthreads();
  for (int t = tid; t < NSEG; t += 256) {
    int col = t % HP, seg = t / HP;
    int r0 = seg * 17, r1 = min(r0 + 17, HP);
    float sum = 0.f;
    for (int i = max(r0-5, 0); i <= min(r0+3, HP-1); ++i) sum += h[i*LSTR + col];
    for (int i = r0; i < r1; ++i) {
      if (i+4 < HP) sum += h[(i+4)*LSTR + col];
      float cr = sum;
      int p = i*HP + col;
      int ii = i + dy, jj = col + dx;
      bool valid = (ii >= 0 && ii < HP && jj >= 0 && jj < HP);
      float dv = 1e10f;
      if (valid && !(dy == 0 && dx == 0))
        dv = n2q[p] + n2db[ii*HP + jj] - 2.f * cr;
      dist[w*QTOT + p] = dv;
      if (i-5 >= 0) sum -= h[(i-5)*LSTR + col];
    }
  }
}

// 8 queries/block, 32 w-groups; wave shfl reductions, 2 barriers per round
__global__ __launch_bounds__(256) void k_weights(const float* __restrict__ ws,
    const float* __restrict__ dist, __hip_bfloat16* __restrict__ wf) {
  __shared__ float mh[32], sh[32];
  int tid = threadIdx.x;
  int qq = tid & (QB-1);
  int q = blockIdx.x * QB + qq;
  bool qok = q < QTOT;
  int qs = qok ? q : (QTOT - 1);
  int wg = tid >> 3;             // 0..31
  int wave = tid >> 6;           // 0..3
  float invT = __expf(-ws[29*QTOT + qs]);
  float lv[NIT], ev[NIT];
#pragma unroll
  for (int it = 0; it < NIT; ++it) {
    int w = wg + it*32;
    lv[it] = (qok && w < NW) ? (-dist[w*QTOT + qs] * invT) : -3.0e38f;
  }
  for (int k = 0; k < KK; ++k) {
    float pm = -3.0e38f;
#pragma unroll
    for (int it = 0; it < NIT; ++it) pm = fmaxf(pm, lv[it]);
    pm = fmaxf(pm, __shfl_xor(pm, 8, 64));
    pm = fmaxf(pm, __shfl_xor(pm, 16, 64));
    pm = fmaxf(pm, __shfl_xor(pm, 32, 64));
    if ((tid & 63) < QB) mh[wave*QB + qq] = pm;
    __syncthreads();
    float m = fmaxf(fmaxf(mh[qq], mh[QB+qq]), fmaxf(mh[2*QB+qq], mh[3*QB+qq]));
    float psum = 0.f;
#pragma unroll
    for (int it = 0; it < NIT; ++it) {
      float e = __expf(lv[it] - m);
      ev[it] = e;
      psum += e;
    }
    psum += __shfl_xor(psum, 8, 64);
    psum += __shfl_xor(psum, 16, 64);
    psum += __shfl_xor(psum, 32, 64);
    if ((tid & 63) < QB) sh[wave*QB + qq] = psum;
    __syncthreads();
    float invden = 1.0f / (sh[qq] + sh[QB+qq] + sh[2*QB+qq] + sh[3*QB+qq]);
#pragma unroll
    for (int it = 0; it < NIT; ++it) {
      int w = wg + it*32;
      if (qok && w < NW) {
        float wgt = ev[it] * invden;
        wf[((size_t)(k*NW + w))*QTOT + q] = __float2bfloat16(wgt);
        if (k < KK-1) lv[it] += __logf(fmaxf(1.f - wgt, 1e-6f));
      }
    }
  }
}

// single-wave (64t) block per (k,w) plane; in-LDS bf16 separable box, sync-free rows/cols
__global__ __launch_bounds__(64) void k_boxw(__hip_bfloat16* __restrict__ wf) {
  __shared__ __hip_bfloat16 a[HP*LSTR];
  __shared__ __hip_bfloat16 h[HP*LSTR];
  __hip_bfloat16* plane = wf + (size_t)blockIdx.x * QTOT;
  int tid = threadIdx.x;
  for (int p = tid; p < QTOT; p += 64)
    a[(p/HP)*LSTR + (p%HP)] = plane[p];
  __syncthreads();
  // horizontal, window [-4,+5]; thread owns a row
  for (int r = tid; r < HP; r += 64) {
    const __hip_bfloat16* ar = a + r*LSTR;
    __hip_bfloat16* hr = h + r*LSTR;
    float sum = 0.f;
#pragma unroll
    for (int j = 0; j < 5; ++j) sum += __bfloat162float(ar[j]);
    for (int j = 0; j < HP; ++j) {
      if (j+5 < HP) sum += __bfloat162float(ar[j+5]);
      hr[j] = __float2bfloat16(sum);
      if (j-4 >= 0) sum -= __bfloat162float(ar[j-4]);
    }
  }
  __syncthreads();
  // vertical, window [-4,+5]; thread owns a column, writes global
  for (int c = tid; c < HP; c += 64) {
    float sum = 0.f;
#pragma unroll
    for (int i = 0; i < 5; ++i) sum += __bfloat162float(h[i*LSTR + c]);
    for (int i = 0; i < HP; ++i) {
      if (i+5 < HP) sum += __bfloat162float(h[(i+5)*LSTR + c]);
      plane[i*HP + c] = __float2bfloat16(sum);
      if (i-4 >= 0) sum -= __bfloat162float(h[(i-4)*LSTR + c]);
    }
  }
}

// grid (16 tiles, NZ, KK): one k per block -> 1680 blocks
__global__ __launch_bounds__(256) void k_contract(const float* __restrict__ ws,
    const __hip_bfloat16* __restrict__ wf, float* __restrict__ accb2) {
  __shared__ float xt[8][18][44];
  int t = blockIdx.x, z = blockIdx.y, k = blockIdx.z, tid = threadIdx.x;
  int I0 = (t >> 2) * 16, J0 = (t & 3) * 16;
  int dylo = -WOFF2 + 2*z;
  int dyhi = (z == NZ-1) ? WOFF2 : (dylo + 1);
  int NRr = 16 + (dyhi - dylo);
  int gy0 = I0 + 1 + dylo, gx0 = J0 - 13;
  const float* x66p = ws + 16*QTOT;
  for (int idx = tid; idx < 8*NRr*44; idx += 256) {
    int c = idx / (NRr*44);
    int rem = idx % (NRr*44);
    int r = rem / 44, cc = rem % 44;
    int gy = gy0 + r, gx = gx0 + cc;
    float v = 0.f;
    if (gy >= 0 && gy < HP && gx >= 0 && gx < HP) v = x66p[c*QTOT + gy*HP + gx];
    xt[c][r][cc] = v;
  }
  __syncthreads();
  int il = tid >> 4, jl = tid & 15;
  int I = I0 + 1 + il, J = J0 + 1 + jl;
  int pix = I*HP + J;
  float acc[8];
#pragma unroll
  for (int c = 0; c < 8; ++c) acc[c] = 0.f;
  int wlo = (dylo + WOFF2) * NWIN, whi = (dyhi + WOFF2 + 1) * NWIN;
  for (int w = wlo; w < whi; ++w) {
    int dyw = w / NWIN - WOFF2, dxw = w % NWIN - WOFF2;
    int r = il + (dyw - dylo), col = jl + dxw + 14;
    float wsv = __bfloat162float(wf[((size_t)(k*NW + w))*QTOT + pix]);
#pragma unroll
    for (int c = 0; c < 8; ++c) acc[c] += wsv * xt[c][r][col];
  }
  int px64 = (I-1)*64 + (J-1);
#pragma unroll
  for (int c = 0; c < 8; ++c)
    accb2[((z*56 + k*8 + c)*4096) + px64] = acc[c];
}

__global__ __launch_bounds__(256) void k_final(const float* __restrict__ y,
    const float* __restrict__ accb2, float* __restrict__ out) {
  int idx = blockIdx.x * 256 + threadIdx.x;
  int ch = idx >> 12, px = idx & 4095;
  if (ch < 8) { out[idx] = y[ch*4096 + px]; return; }
  int kc = ch - 8, c = kc & 7;
  int i = px >> 6, j = px & 63;
  int I = i + 1, J = j + 1;
  int cy = min(I+5, HP-1) - max(I-4, 0) + 1;
  int cx = min(J+5, HP-1) - max(J-4, 0) + 1;
  float s = 0.f;
  for (int z = 0; z < NZ; ++z) s += accb2[(z*56 + kc)*4096 + px];
  out[idx] = s / (float)(cy*cx) - y[c*4096 + px];
}

extern "C" void kernel_launch(void* const* d_in, const int* in_sizes, int n_in,
                              void* d_out, int out_size, void* d_ws, size_t ws_size,
                              hipStream_t stream) {
  const float* x  = (const float*)d_in[0];
  const float* xe = (const float*)d_in[1];
  const float* ye = (const float*)d_in[2];
  const float* y  = (const float*)d_in[3];
  const float* lt = (const float*)d_in[4];
  float* ws   = (float*)d_ws;
  float* dist = ws + 30*QTOT;
  __hip_bfloat16* wf = (__hip_bfloat16*)(dist + (size_t)NW*QTOT);
  float* accb2 = dist;
  float* out = (float*)d_out;

  k_prep1<<<(QTOT + 255)/256, 256, 0, stream>>>(x, xe, ye, lt, ws);
  k_prep2<<<(QTOT + 255)/256, 256, 0, stream>>>(ws);
  k_dist<<<NW, 256, 0, stream>>>(ws, dist);
  k_weights<<<(QTOT + QB - 1)/QB, 256, 0, stream>>>(ws, dist, wf);
  k_boxw<<<KK*NW, 64, 0, stream>>>(wf);
  k_contract<<<dim3(16, NZ, KK), 256, 0, stream>>>(ws, wf, accb2);
  k_final<<<out_size/256, 256, 0, stream>>>(y, accb2, out);
}

// Round 5
// 201.084 us; speedup vs baseline: 1.2000x; 1.2000x over previous
//
#include <hip/hip_runtime.h>
#include <hip/hip_bf16.h>

#define HP    66
#define QTOT  (HP*HP)          // 4356
#define LSTR  67               // padded LDS row stride
#define NWIN  29
#define NW    (NWIN*NWIN)      // 841
#define KK    7
#define WOFF2 14
#define NZ    15               // dy-chunks for contraction
#define QB    8                // queries per k_weights block
#define NIT   27               // ceil(841/32)
#define NSEG3 198              // 66 lines x 3 segments of 22

// ws float layout:
// 0        : ye66   8*QTOT
// 8*QTOT   : xe66   8*QTOT
// 16*QTOT  : x66p   8*QTOT
// 24*QTOT  : sqye   QTOT
// 25*QTOT  : sqxe   QTOT
// 26*QTOT  : lt66   QTOT
// 27*QTOT  : n2q    QTOT
// 28*QTOT  : n2db   QTOT
// 29*QTOT  : ltb    QTOT
// 30*QTOT  : dist   NW*QTOT f32      (reused as accb2 after k_weights)
// 30*QTOT + NW*QTOT : wf  KK*NW*QTOT bf16

__global__ __launch_bounds__(256) void k_prep1(const float* __restrict__ x,
    const float* __restrict__ xe, const float* __restrict__ ye,
    const float* __restrict__ lt, float* __restrict__ ws) {
  int p = blockIdx.x * 256 + threadIdx.x;
  if (p >= QTOT) return;
  int i = p / HP, j = p % HP;
  bool in = (i >= 1 && i < HP-1 && j >= 1 && j < HP-1);
  int src = (i-1)*64 + (j-1);
  float* ye66 = ws;
  float* xe66 = ws + 8*QTOT;
  float* x66p = ws + 16*QTOT;
  float sy = 0.f, sx = 0.f;
#pragma unroll
  for (int e = 0; e < 8; ++e) {
    float vy = in ? ye[e*4096 + src] : 0.f;
    float vx = in ? xe[e*4096 + src] : 0.f;
    float vv = in ? x [e*4096 + src] : 0.f;
    ye66[e*QTOT + p] = vy;
    xe66[e*QTOT + p] = vx;
    x66p[e*QTOT + p] = vv;
    sy += vy*vy; sx += vx*vx;
  }
  ws[24*QTOT + p] = sy;
  ws[25*QTOT + p] = sx;
  ws[26*QTOT + p] = in ? lt[src] : 0.f;
}

__global__ __launch_bounds__(256) void k_prep2(float* __restrict__ ws) {
  int p = blockIdx.x * 256 + threadIdx.x;
  if (p >= QTOT) return;
  int i = p / HP, j = p % HP;
  const float* sqye = ws + 24*QTOT;
  const float* sqxe = ws + 25*QTOT;
  const float* lt66 = ws + 26*QTOT;
  float a = 0.f, b = 0.f, c = 0.f;
  for (int u = -5; u <= 4; ++u) {
    int ii = i + u; if (ii < 0 || ii >= HP) continue;
    for (int v = -5; v <= 4; ++v) {
      int jj = j + v; if (jj < 0 || jj >= HP) continue;
      int o = ii*HP + jj;
      a += sqye[o]; b += sqxe[o]; c += lt66[o];
    }
  }
  ws[27*QTOT + p] = a;
  ws[28*QTOT + p] = b;
  ws[29*QTOT + p] = c * 0.01f;
}

// one block per shift w: dist plane [w][q].
// Box window [-5,+4] via register-rotation sliding sums (fully unrolled).
__global__ __launch_bounds__(256) void k_dist(const float* __restrict__ ws,
                                              float* __restrict__ dist) {
  __shared__ float s[HP*LSTR];
  __shared__ float h[HP*LSTR];
  int w = blockIdx.x, tid = threadIdx.x;
  int dy = w / NWIN - WOFF2, dx = w % NWIN - WOFF2;
  const float* ye66 = ws;
  const float* xe66 = ws + 8*QTOT;
  const float* n2q  = ws + 27*QTOT;
  const float* n2db = ws + 28*QTOT;
  for (int p = tid; p < QTOT; p += 256) {
    int i = p / HP, j = p % HP;
    int ii = i + dy, jj = j + dx;
    float sv = 0.f;
    if (ii >= 0 && ii < HP && jj >= 0 && jj < HP) {
      int p2 = ii*HP + jj;
#pragma unroll
      for (int e = 0; e < 8; ++e) sv += ye66[e*QTOT + p] * xe66[e*QTOT + p2];
    }
    s[i*LSTR + j] = sv;
  }
  __syncthreads();
  // horizontal, window [-5,+4]
  if (tid < NSEG3) {
    int row = tid % HP, seg = tid / HP, c0 = seg*22;
    const float* ar = s + row*LSTR;
    float* hr = h + row*LSTR;
    float w9[9]; float sum = 0.f;
#pragma unroll
    for (int t = 0; t < 9; ++t) {
      int jj = c0 - 5 + t;
      float v = (jj >= 0) ? ar[jj] : 0.f;     // jj <= c0+3 <= 47 < HP
      w9[t] = v; sum += v;
    }
#pragma unroll
    for (int t = 0; t < 22; ++t) {
      int j = c0 + t, jn = j + 4;
      float nv = (jn < HP) ? ar[jn] : 0.f;
      sum += nv;
      hr[j] = sum;
      sum -= w9[t % 9];
      w9[t % 9] = nv;
    }
  }
  __syncthreads();
  // vertical, window [-5,+4], + dist epilogue
  if (tid < NSEG3) {
    int col = tid % HP, seg = tid / HP, r0 = seg*22;
    float w9[9]; float sum = 0.f;
#pragma unroll
    for (int t = 0; t < 9; ++t) {
      int ii = r0 - 5 + t;
      float v = (ii >= 0) ? h[ii*LSTR + col] : 0.f;
      w9[t] = v; sum += v;
    }
#pragma unroll
    for (int t = 0; t < 22; ++t) {
      int i = r0 + t, in2 = i + 4;
      float nv = (in2 < HP) ? h[in2*LSTR + col] : 0.f;
      sum += nv;
      float cr = sum;
      int p = i*HP + col;
      int ii = i + dy, jj = col + dx;
      bool valid = (ii >= 0 && ii < HP && jj >= 0 && jj < HP);
      float dv = 1e10f;
      if (valid && !(dy == 0 && dx == 0))
        dv = n2q[p] + n2db[ii*HP + jj] - 2.f * cr;
      dist[w*QTOT + p] = dv;
      sum -= w9[t % 9];
      w9[t % 9] = nv;
    }
  }
}

// 8 queries/block, 32 w-groups; wave shfl reductions
__global__ __launch_bounds__(256) void k_weights(const float* __restrict__ ws,
    const float* __restrict__ dist, __hip_bfloat16* __restrict__ wf) {
  __shared__ float mh[32], sh[32];
  int tid = threadIdx.x;
  int qq = tid & (QB-1);
  int q = blockIdx.x * QB + qq;
  bool qok = q < QTOT;
  int qs = qok ? q : (QTOT - 1);
  int wg = tid >> 3;             // 0..31
  int wave = tid >> 6;           // 0..3
  float invT = __expf(-ws[29*QTOT + qs]);
  float lv[NIT], ev[NIT];
#pragma unroll
  for (int it = 0; it < NIT; ++it) {
    int w = wg + it*32;
    lv[it] = (qok && w < NW) ? (-dist[w*QTOT + qs] * invT) : -3.0e38f;
  }
  for (int k = 0; k < KK; ++k) {
    float pm = -3.0e38f;
#pragma unroll
    for (int it = 0; it < NIT; ++it) pm = fmaxf(pm, lv[it]);
    pm = fmaxf(pm, __shfl_xor(pm, 8, 64));
    pm = fmaxf(pm, __shfl_xor(pm, 16, 64));
    pm = fmaxf(pm, __shfl_xor(pm, 32, 64));
    if ((tid & 63) < QB) mh[wave*QB + qq] = pm;
    __syncthreads();
    float m = fmaxf(fmaxf(mh[qq], mh[QB+qq]), fmaxf(mh[2*QB+qq], mh[3*QB+qq]));
    float psum = 0.f;
#pragma unroll
    for (int it = 0; it < NIT; ++it) {
      float e = __expf(lv[it] - m);
      ev[it] = e;
      psum += e;
    }
    psum += __shfl_xor(psum, 8, 64);
    psum += __shfl_xor(psum, 16, 64);
    psum += __shfl_xor(psum, 32, 64);
    if ((tid & 63) < QB) sh[wave*QB + qq] = psum;
    __syncthreads();
    float invden = 1.0f / (sh[qq] + sh[QB+qq] + sh[2*QB+qq] + sh[3*QB+qq]);
#pragma unroll
    for (int it = 0; it < NIT; ++it) {
      int w = wg + it*32;
      if (qok && w < NW) {
        float wgt = ev[it] * invden;
        wf[((size_t)(k*NW + w))*QTOT + q] = __float2bfloat16(wgt);
        if (k < KK-1) lv[it] += __logf(fmaxf(1.f - wgt, 1e-6f));
      }
    }
  }
}

// one 256t block per (k,w) plane; bf16 in/out, f32 mid; register-rotation sliding;
// window [-4,+5]; packed uint plane load/store
__global__ __launch_bounds__(256) void k_boxw(__hip_bfloat16* __restrict__ wf) {
  __shared__ __hip_bfloat16 a[HP*LSTR];
  __shared__ float h[HP*LSTR];
  __hip_bfloat16* plane = wf + (size_t)blockIdx.x * QTOT;
  const unsigned* up = (const unsigned*)plane;
  unsigned* upw = (unsigned*)plane;
  int tid = threadIdx.x;
  // load (QTOT even: 2178 uints)
  for (int u = tid; u < QTOT/2; u += 256) {
    unsigned v = up[u];
    int p0 = 2*u, p1 = 2*u + 1;
    a[(p0/HP)*LSTR + p0%HP] = __ushort_as_bfloat16((unsigned short)(v & 0xffffu));
    a[(p1/HP)*LSTR + p1%HP] = __ushort_as_bfloat16((unsigned short)(v >> 16));
  }
  __syncthreads();
  // horizontal, window [-4,+5]
  if (tid < NSEG3) {
    int row = tid % HP, seg = tid / HP, c0 = seg*22;
    const __hip_bfloat16* ar = a + row*LSTR;
    float* hr = h + row*LSTR;
    float w9[9]; float sum = 0.f;
#pragma unroll
    for (int t = 0; t < 9; ++t) {
      int jj = c0 - 4 + t;
      float v = (jj >= 0) ? __bfloat162float(ar[jj]) : 0.f;  // jj <= c0+4 < HP
      w9[t] = v; sum += v;
    }
#pragma unroll
    for (int t = 0; t < 22; ++t) {
      int j = c0 + t, jn = j + 5;
      float nv = (jn < HP) ? __bfloat162float(ar[jn]) : 0.f;
      sum += nv;
      hr[j] = sum;
      sum -= w9[t % 9];
      w9[t % 9] = nv;
    }
  }
  __syncthreads();
  // vertical, window [-4,+5]; result back into a (bf16)
  if (tid < NSEG3) {
    int col = tid % HP, seg = tid / HP, r0 = seg*22;
    float w9[9]; float sum = 0.f;
#pragma unroll
    for (int t = 0; t < 9; ++t) {
      int ii = r0 - 4 + t;
      float v = (ii >= 0) ? h[ii*LSTR + col] : 0.f;
      w9[t] = v; sum += v;
    }
#pragma unroll
    for (int t = 0; t < 22; ++t) {
      int i = r0 + t, in2 = i + 5;
      float nv = (in2 < HP) ? h[in2*LSTR + col] : 0.f;
      sum += nv;
      a[i*LSTR + col] = __float2bfloat16(sum);
      sum -= w9[t % 9];
      w9[t % 9] = nv;
    }
  }
  __syncthreads();
  // packed coalesced store
  for (int u = tid; u < QTOT/2; u += 256) {
    int p0 = 2*u, p1 = 2*u + 1;
    unsigned lo = __bfloat16_as_ushort(a[(p0/HP)*LSTR + p0%HP]);
    unsigned hi = __bfloat16_as_ushort(a[(p1/HP)*LSTR + p1%HP]);
    upw[u] = lo | (hi << 16);
  }
}

// grid (16 tiles, NZ, KK)
__global__ __launch_bounds__(256) void k_contract(const float* __restrict__ ws,
    const __hip_bfloat16* __restrict__ wf, float* __restrict__ accb2) {
  __shared__ float xt[8][18][44];
  int t = blockIdx.x, z = blockIdx.y, k = blockIdx.z, tid = threadIdx.x;
  int I0 = (t >> 2) * 16, J0 = (t & 3) * 16;
  int dylo = -WOFF2 + 2*z;
  int dyhi = (z == NZ-1) ? WOFF2 : (dylo + 1);
  int NRr = 16 + (dyhi - dylo);
  int gy0 = I0 + 1 + dylo, gx0 = J0 - 13;
  const float* x66p = ws + 16*QTOT;
  for (int idx = tid; idx < 8*NRr*44; idx += 256) {
    int c = idx / (NRr*44);
    int rem = idx % (NRr*44);
    int r = rem / 44, cc = rem % 44;
    int gy = gy0 + r, gx = gx0 + cc;
    float v = 0.f;
    if (gy >= 0 && gy < HP && gx >= 0 && gx < HP) v = x66p[c*QTOT + gy*HP + gx];
    xt[c][r][cc] = v;
  }
  __syncthreads();
  int il = tid >> 4, jl = tid & 15;
  int I = I0 + 1 + il, J = J0 + 1 + jl;
  int pix = I*HP + J;
  float acc[8];
#pragma unroll
  for (int c = 0; c < 8; ++c) acc[c] = 0.f;
  int wlo = (dylo + WOFF2) * NWIN, whi = (dyhi + WOFF2 + 1) * NWIN;
  for (int w = wlo; w < whi; ++w) {
    int dyw = w / NWIN - WOFF2, dxw = w % NWIN - WOFF2;
    int r = il + (dyw - dylo), col = jl + dxw + 14;
    float wsv = __bfloat162float(wf[((size_t)(k*NW + w))*QTOT + pix]);
#pragma unroll
    for (int c = 0; c < 8; ++c) acc[c] += wsv * xt[c][r][col];
  }
  int px64 = (I-1)*64 + (J-1);
#pragma unroll
  for (int c = 0; c < 8; ++c)
    accb2[((z*56 + k*8 + c)*4096) + px64] = acc[c];
}

__global__ __launch_bounds__(256) void k_final(const float* __restrict__ y,
    const float* __restrict__ accb2, float* __restrict__ out) {
  int idx = blockIdx.x * 256 + threadIdx.x;
  int ch = idx >> 12, px = idx & 4095;
  if (ch < 8) { out[idx] = y[ch*4096 + px]; return; }
  int kc = ch - 8, c = kc & 7;
  int i = px >> 6, j = px & 63;
  int I = i + 1, J = j + 1;
  int cy = min(I+5, HP-1) - max(I-4, 0) + 1;
  int cx = min(J+5, HP-1) - max(J-4, 0) + 1;
  float s = 0.f;
  for (int z = 0; z < NZ; ++z) s += accb2[(z*56 + kc)*4096 + px];
  out[idx] = s / (float)(cy*cx) - y[c*4096 + px];
}

extern "C" void kernel_launch(void* const* d_in, const int* in_sizes, int n_in,
                              void* d_out, int out_size, void* d_ws, size_t ws_size,
                              hipStream_t stream) {
  const float* x  = (const float*)d_in[0];
  const float* xe = (const float*)d_in[1];
  const float* ye = (const float*)d_in[2];
  const float* y  = (const float*)d_in[3];
  const float* lt = (const float*)d_in[4];
  float* ws   = (float*)d_ws;
  float* dist = ws + 30*QTOT;
  __hip_bfloat16* wf = (__hip_bfloat16*)(dist + (size_t)NW*QTOT);
  float* accb2 = dist;
  float* out = (float*)d_out;

  k_prep1<<<(QTOT + 255)/256, 256, 0, stream>>>(x, xe, ye, lt, ws);
  k_prep2<<<(QTOT + 255)/256, 256, 0, stream>>>(ws);
  k_dist<<<NW, 256, 0, stream>>>(ws, dist);
  k_weights<<<(QTOT + QB - 1)/QB, 256, 0, stream>>>(ws, dist, wf);
  k_boxw<<<KK*NW, 256, 0, stream>>>(wf);
  k_contract<<<dim3(16, NZ, KK), 256, 0, stream>>>(ws, wf, accb2);
  k_final<<<out_size/256, 256, 0, stream>>>(y, accb2, out);
}

// Round 6
// 179.356 us; speedup vs baseline: 1.3453x; 1.1211x over previous
//
#include <hip/hip_runtime.h>
#include <hip/hip_bf16.h>

#define HP    66
#define QTOT  (HP*HP)          // 4356
#define LSTR  67               // padded LDS row stride
#define NWIN  29
#define NW    (NWIN*NWIN)      // 841
#define KK    7
#define WOFF2 14
#define NZ    15               // dy-chunks for contraction
#define QB    8                // queries per k_weights block
#define QBN   545              // ceil(QTOT/8)
#define NIT   27               // ceil(841/32)
#define NSEG3 198              // 66 lines x 3 segments of 22

// ws float layout:
// 0        : ye66   8*QTOT
// 8*QTOT   : xe66   8*QTOT
// 16*QTOT  : x66p   8*QTOT
// 24*QTOT  : sqye   QTOT
// 25*QTOT  : sqxe   QTOT
// 26*QTOT  : lt66   QTOT
// 27*QTOT  : n2q    QTOT
// 28*QTOT  : n2db   QTOT
// 29*QTOT  : ltb    QTOT
// 30*QTOT  : dist   NW*QTOT f32      (reused as accb2 after k_weights)
// 30*QTOT + NW*QTOT : wf  bf16 [k][qb][w][8q]  (KK*QBN*NW*8 elems)

__global__ __launch_bounds__(256) void k_prep1(const float* __restrict__ x,
    const float* __restrict__ xe, const float* __restrict__ ye,
    const float* __restrict__ lt, float* __restrict__ ws) {
  int p = blockIdx.x * 256 + threadIdx.x;
  if (p >= QTOT) return;
  int i = p / HP, j = p % HP;
  bool in = (i >= 1 && i < HP-1 && j >= 1 && j < HP-1);
  int src = (i-1)*64 + (j-1);
  float* ye66 = ws;
  float* xe66 = ws + 8*QTOT;
  float* x66p = ws + 16*QTOT;
  float sy = 0.f, sx = 0.f;
#pragma unroll
  for (int e = 0; e < 8; ++e) {
    float vy = in ? ye[e*4096 + src] : 0.f;
    float vx = in ? xe[e*4096 + src] : 0.f;
    float vv = in ? x [e*4096 + src] : 0.f;
    ye66[e*QTOT + p] = vy;
    xe66[e*QTOT + p] = vx;
    x66p[e*QTOT + p] = vv;
    sy += vy*vy; sx += vx*vx;
  }
  ws[24*QTOT + p] = sy;
  ws[25*QTOT + p] = sx;
  ws[26*QTOT + p] = in ? lt[src] : 0.f;
}

__global__ __launch_bounds__(256) void k_prep2(float* __restrict__ ws) {
  int p = blockIdx.x * 256 + threadIdx.x;
  if (p >= QTOT) return;
  int i = p / HP, j = p % HP;
  const float* sqye = ws + 24*QTOT;
  const float* sqxe = ws + 25*QTOT;
  const float* lt66 = ws + 26*QTOT;
  float a = 0.f, b = 0.f, c = 0.f;
  for (int u = -5; u <= 4; ++u) {
    int ii = i + u; if (ii < 0 || ii >= HP) continue;
    for (int v = -5; v <= 4; ++v) {
      int jj = j + v; if (jj < 0 || jj >= HP) continue;
      int o = ii*HP + jj;
      a += sqye[o]; b += sqxe[o]; c += lt66[o];
    }
  }
  ws[27*QTOT + p] = a;
  ws[28*QTOT + p] = b;
  ws[29*QTOT + p] = c * 0.01f;
}

// one block per shift w: dist plane [w][q]; register-rotation sliding box [-5,+4]
__global__ __launch_bounds__(256) void k_dist(const float* __restrict__ ws,
                                              float* __restrict__ dist) {
  __shared__ float s[HP*LSTR];
  __shared__ float h[HP*LSTR];
  int w = blockIdx.x, tid = threadIdx.x;
  int dy = w / NWIN - WOFF2, dx = w % NWIN - WOFF2;
  const float* ye66 = ws;
  const float* xe66 = ws + 8*QTOT;
  const float* n2q  = ws + 27*QTOT;
  const float* n2db = ws + 28*QTOT;
  for (int p = tid; p < QTOT; p += 256) {
    int i = p / HP, j = p % HP;
    int ii = i + dy, jj = j + dx;
    float sv = 0.f;
    if (ii >= 0 && ii < HP && jj >= 0 && jj < HP) {
      int p2 = ii*HP + jj;
#pragma unroll
      for (int e = 0; e < 8; ++e) sv += ye66[e*QTOT + p] * xe66[e*QTOT + p2];
    }
    s[i*LSTR + j] = sv;
  }
  __syncthreads();
  if (tid < NSEG3) {
    int row = tid % HP, seg = tid / HP, c0 = seg*22;
    const float* ar = s + row*LSTR;
    float* hr = h + row*LSTR;
    float w9[9]; float sum = 0.f;
#pragma unroll
    for (int t = 0; t < 9; ++t) {
      int jj = c0 - 5 + t;
      float v = (jj >= 0) ? ar[jj] : 0.f;
      w9[t] = v; sum += v;
    }
#pragma unroll
    for (int t = 0; t < 22; ++t) {
      int j = c0 + t, jn = j + 4;
      float nv = (jn < HP) ? ar[jn] : 0.f;
      sum += nv;
      hr[j] = sum;
      sum -= w9[t % 9];
      w9[t % 9] = nv;
    }
  }
  __syncthreads();
  if (tid < NSEG3) {
    int col = tid % HP, seg = tid / HP, r0 = seg*22;
    float w9[9]; float sum = 0.f;
#pragma unroll
    for (int t = 0; t < 9; ++t) {
      int ii = r0 - 5 + t;
      float v = (ii >= 0) ? h[ii*LSTR + col] : 0.f;
      w9[t] = v; sum += v;
    }
#pragma unroll
    for (int t = 0; t < 22; ++t) {
      int i = r0 + t, in2 = i + 4;
      float nv = (in2 < HP) ? h[in2*LSTR + col] : 0.f;
      sum += nv;
      float cr = sum;
      int p = i*HP + col;
      int ii = i + dy, jj = col + dx;
      bool valid = (ii >= 0 && ii < HP && jj >= 0 && jj < HP);
      float dv = 1e10f;
      if (valid && !(dy == 0 && dx == 0))
        dv = n2q[p] + n2db[ii*HP + jj] - 2.f * cr;
      dist[w*QTOT + p] = dv;
      sum -= w9[t % 9];
      w9[t % 9] = nv;
    }
  }
}

// 8 queries/block; writes wf[k][qb][w][8q] -> 128B contiguous per wave store
__global__ __launch_bounds__(256) void k_weights(const float* __restrict__ ws,
    const float* __restrict__ dist, __hip_bfloat16* __restrict__ wf) {
  __shared__ float mh[32], sh[32];
  int tid = threadIdx.x;
  int qq = tid & (QB-1);
  int qb = blockIdx.x;
  int q = qb * QB + qq;
  bool qok = q < QTOT;
  int qs = qok ? q : (QTOT - 1);
  int wg = tid >> 3;             // 0..31
  int wave = tid >> 6;           // 0..3
  float invT = __expf(-ws[29*QTOT + qs]);
  float lv[NIT], ev[NIT];
#pragma unroll
  for (int it = 0; it < NIT; ++it) {
    int w = wg + it*32;
    lv[it] = (qok && w < NW) ? (-dist[w*QTOT + qs] * invT) : -3.0e38f;
  }
  for (int k = 0; k < KK; ++k) {
    float pm = -3.0e38f;
#pragma unroll
    for (int it = 0; it < NIT; ++it) pm = fmaxf(pm, lv[it]);
    pm = fmaxf(pm, __shfl_xor(pm, 8, 64));
    pm = fmaxf(pm, __shfl_xor(pm, 16, 64));
    pm = fmaxf(pm, __shfl_xor(pm, 32, 64));
    if ((tid & 63) < QB) mh[wave*QB + qq] = pm;
    __syncthreads();
    float m = fmaxf(fmaxf(mh[qq], mh[QB+qq]), fmaxf(mh[2*QB+qq], mh[3*QB+qq]));
    float psum = 0.f;
#pragma unroll
    for (int it = 0; it < NIT; ++it) {
      float e = __expf(lv[it] - m);
      ev[it] = e;
      psum += e;
    }
    psum += __shfl_xor(psum, 8, 64);
    psum += __shfl_xor(psum, 16, 64);
    psum += __shfl_xor(psum, 32, 64);
    if ((tid & 63) < QB) sh[wave*QB + qq] = psum;
    __syncthreads();
    float invden = 1.0f / (sh[qq] + sh[QB+qq] + sh[2*QB+qq] + sh[3*QB+qq]);
    size_t bkq = ((size_t)k*QBN + qb)*NW;
#pragma unroll
    for (int it = 0; it < NIT; ++it) {
      int w = wg + it*32;
      if (qok && w < NW) {
        float wgt = ev[it] * invden;
        wf[(bkq + w)*8 + qq] = __float2bfloat16(wgt);
        if (k < KK-1 && wgt > 1e-9f)
          lv[it] += __logf(fmaxf(1.f - wgt, 1e-6f));
      }
    }
    __syncthreads();
  }
}

// one 256t block per (k,w) plane (XCD-chunk-swizzled); uint4 gather/scatter of
// 8q fragments; bf16 in/out, f32 mid; register-rotation sliding window [-4,+5]
__global__ __launch_bounds__(256) void k_boxw(__hip_bfloat16* __restrict__ wfp) {
  __shared__ __hip_bfloat16 a[HP*LSTR];
  __shared__ float h[HP*LSTR];
  int bid = blockIdx.x;
  int l = (bid & 7)*736 + (bid >> 3);      // bijective on 0..5886
  if (l >= KK*NW) return;
  int k = l / NW, w = l % NW;
  uint4* u4 = (uint4*)wfp;                 // one uint4 = 8 bf16 (one qb fragment)
  size_t pb = ((size_t)k*QBN)*NW + w;
  int tid = threadIdx.x;
  for (int qb = tid; qb < QBN; qb += 256) {
    uint4 v = u4[pb + (size_t)qb*NW];
    unsigned wd[4] = {v.x, v.y, v.z, v.w};
    int p = qb*8;
    int i = p / HP, j = p - i*HP;
#pragma unroll
    for (int e = 0; e < 8; ++e) {
      if (p + e < QTOT) {
        unsigned short u16 = (e & 1) ? (unsigned short)(wd[e>>1] >> 16)
                                     : (unsigned short)(wd[e>>1] & 0xffffu);
        a[i*LSTR + j] = __ushort_as_bfloat16(u16);
      }
      if (++j == HP) { j = 0; ++i; }
    }
  }
  __syncthreads();
  // horizontal, window [-4,+5]
  if (tid < NSEG3) {
    int row = tid % HP, seg = tid / HP, c0 = seg*22;
    const __hip_bfloat16* ar = a + row*LSTR;
    float* hr = h + row*LSTR;
    float w9[9]; float sum = 0.f;
#pragma unroll
    for (int t = 0; t < 9; ++t) {
      int jj = c0 - 4 + t;
      float v = (jj >= 0) ? __bfloat162float(ar[jj]) : 0.f;
      w9[t] = v; sum += v;
    }
#pragma unroll
    for (int t = 0; t < 22; ++t) {
      int j = c0 + t, jn = j + 5;
      float nv = (jn < HP) ? __bfloat162float(ar[jn]) : 0.f;
      sum += nv;
      hr[j] = sum;
      sum -= w9[t % 9];
      w9[t % 9] = nv;
    }
  }
  __syncthreads();
  // vertical, window [-4,+5]; result back into a (bf16)
  if (tid < NSEG3) {
    int col = tid % HP, seg = tid / HP, r0 = seg*22;
    float w9[9]; float sum = 0.f;
#pragma unroll
    for (int t = 0; t < 9; ++t) {
      int ii = r0 - 4 + t;
      float v = (ii >= 0) ? h[ii*LSTR + col] : 0.f;
      w9[t] = v; sum += v;
    }
#pragma unroll
    for (int t = 0; t < 22; ++t) {
      int i = r0 + t, in2 = i + 5;
      float nv = (in2 < HP) ? h[in2*LSTR + col] : 0.f;
      sum += nv;
      a[i*LSTR + col] = __float2bfloat16(sum);
      sum -= w9[t % 9];
      w9[t % 9] = nv;
    }
  }
  __syncthreads();
  for (int qb = tid; qb < QBN; qb += 256) {
    int p = qb*8;
    int i = p / HP, j = p - i*HP;
    unsigned wd[4] = {0u, 0u, 0u, 0u};
#pragma unroll
    for (int e = 0; e < 8; ++e) {
      unsigned u16 = 0;
      if (p + e < QTOT) u16 = __bfloat16_as_ushort(a[i*LSTR + j]);
      wd[e>>1] |= (e & 1) ? (u16 << 16) : u16;
      if (++j == HP) { j = 0; ++i; }
    }
    uint4 v; v.x = wd[0]; v.y = wd[1]; v.z = wd[2]; v.w = wd[3];
    u4[pb + (size_t)qb*NW] = v;
  }
}

// grid (16 tiles, NZ, KK)
__global__ __launch_bounds__(256) void k_contract(const float* __restrict__ ws,
    const __hip_bfloat16* __restrict__ wf, float* __restrict__ accb2) {
  __shared__ float xt[8][18][44];
  int t = blockIdx.x, z = blockIdx.y, k = blockIdx.z, tid = threadIdx.x;
  int I0 = (t >> 2) * 16, J0 = (t & 3) * 16;
  int dylo = -WOFF2 + 2*z;
  int dyhi = (z == NZ-1) ? WOFF2 : (dylo + 1);
  int NRr = 16 + (dyhi - dylo);
  int gy0 = I0 + 1 + dylo, gx0 = J0 - 13;
  const float* x66p = ws + 16*QTOT;
  for (int idx = tid; idx < 8*NRr*44; idx += 256) {
    int c = idx / (NRr*44);
    int rem = idx % (NRr*44);
    int r = rem / 44, cc = rem % 44;
    int gy = gy0 + r, gx = gx0 + cc;
    float v = 0.f;
    if (gy >= 0 && gy < HP && gx >= 0 && gx < HP) v = x66p[c*QTOT + gy*HP + gx];
    xt[c][r][cc] = v;
  }
  __syncthreads();
  int il = tid >> 4, jl = tid & 15;
  int I = I0 + 1 + il, J = J0 + 1 + jl;
  int pix = I*HP + J;
  int qb = pix >> 3, q7 = pix & 7;
  size_t cbase = (((size_t)k*QBN + qb)*NW)*8 + q7;
  float acc[8];
#pragma unroll
  for (int c = 0; c < 8; ++c) acc[c] = 0.f;
  int wlo = (dylo + WOFF2) * NWIN, whi = (dyhi + WOFF2 + 1) * NWIN;
  for (int w = wlo; w < whi; ++w) {
    int dyw = w / NWIN - WOFF2, dxw = w % NWIN - WOFF2;
    int r = il + (dyw - dylo), col = jl + dxw + 14;
    float wsv = __bfloat162float(wf[cbase + (size_t)w*8]);
#pragma unroll
    for (int c = 0; c < 8; ++c) acc[c] += wsv * xt[c][r][col];
  }
  int px64 = (I-1)*64 + (J-1);
#pragma unroll
  for (int c = 0; c < 8; ++c)
    accb2[((z*56 + k*8 + c)*4096) + px64] = acc[c];
}

__global__ __launch_bounds__(256) void k_final(const float* __restrict__ y,
    const float* __restrict__ accb2, float* __restrict__ out) {
  int idx = blockIdx.x * 256 + threadIdx.x;
  int ch = idx >> 12, px = idx & 4095;
  if (ch < 8) { out[idx] = y[ch*4096 + px]; return; }
  int kc = ch - 8, c = kc & 7;
  int i = px >> 6, j = px & 63;
  int I = i + 1, J = j + 1;
  int cy = min(I+5, HP-1) - max(I-4, 0) + 1;
  int cx = min(J+5, HP-1) - max(J-4, 0) + 1;
  float s = 0.f;
  for (int z = 0; z < NZ; ++z) s += accb2[(z*56 + kc)*4096 + px];
  out[idx] = s / (float)(cy*cx) - y[c*4096 + px];
}

extern "C" void kernel_launch(void* const* d_in, const int* in_sizes, int n_in,
                              void* d_out, int out_size, void* d_ws, size_t ws_size,
                              hipStream_t stream) {
  const float* x  = (const float*)d_in[0];
  const float* xe = (const float*)d_in[1];
  const float* ye = (const float*)d_in[2];
  const float* y  = (const float*)d_in[3];
  const float* lt = (const float*)d_in[4];
  float* ws   = (float*)d_ws;
  float* dist = ws + 30*QTOT;
  __hip_bfloat16* wf = (__hip_bfloat16*)(dist + (size_t)NW*QTOT);
  float* accb2 = dist;
  float* out = (float*)d_out;

  k_prep1<<<(QTOT + 255)/256, 256, 0, stream>>>(x, xe, ye, lt, ws);
  k_prep2<<<(QTOT + 255)/256, 256, 0, stream>>>(ws);
  k_dist<<<NW, 256, 0, stream>>>(ws, dist);
  k_weights<<<QBN, 256, 0, stream>>>(ws, dist, wf);
  k_boxw<<<KK*NW, 256, 0, stream>>>(wf);
  k_contract<<<dim3(16, NZ, KK), 256, 0, stream>>>(ws, wf, accb2);
  k_final<<<out_size/256, 256, 0, stream>>>(y, accb2, out);
}